// Round 2
// baseline (302.010 us; speedup 1.0000x reference)
//
#include <hip/hip_runtime.h>
#include <hip/hip_bf16.h>

// MHA: B=4 L=2048 D=1024 H=16 DH=64, causal. Inputs f32 (sniffed; dtype-proof).
// Round 9: attn_k was serialization-bound (stage -> barrier(vmcnt0 drain) -> compute
// exposed full L2 latency per 64-key tile; neither pipe saturated: VALU floor ~13us
// vs 77us measured). Restructure:
//  - K/V double-buffer, stage NEXT tile before computing current, ONE __syncthreads
//    per tile at the end (T3 minimum 2-phase: barrier's vmcnt(0) drain is hidden
//    under ~1000cyc of compute).
//  - QBLK=128: two q-subtiles per wave share each K/V tile's LDS frags -> staging,
//    barriers, and K/V traffic per unit work halve. Causal: sub0 diag at kt=2qt,
//    sub0 skipped at kt=2qt+1 (fully masked), sub1 diag at kt=2qt+1.
// Softmax stays R8 (exp2 domain, MFMA ones row-sum, defer-max THR=8).

typedef __bf16 bf16;
typedef __bf16 bf16x4 __attribute__((ext_vector_type(4)));
typedef __bf16 bf16x8 __attribute__((ext_vector_type(8)));
typedef float f32x4 __attribute__((ext_vector_type(4)));

#define DEV static __device__ __forceinline__

constexpr int B = 4, L = 2048, D = 1024, H = 16, DH = 64;
constexpr int BL = B * L;                      // 8192
constexpr int GM = 8192, GK = 1024;
constexpr int BKg = 64;                        // GEMM K-tile
constexpr int PST = 72;                        // padded P row stride (elements)

typedef __attribute__((address_space(1))) const void* gptr1;
typedef __attribute__((address_space(3))) void* lptr3;

DEV void load_lds16(const bf16* g, bf16* l) {
  __builtin_amdgcn_global_load_lds((gptr1)g, (lptr3)l, 16, 0, 0);
}

DEV f32x4 mfma(bf16x8 a, bf16x8 b, f32x4 c) {
  return __builtin_amdgcn_mfma_f32_16x16x32_bf16(a, b, c, 0, 0, 0);
}

DEV float scrub(float v) { return (v == v) ? v : 0.f; }

// ---------- dtype sniff (flag=1: bf16 storage, 0: f32) ----------
__global__ void sniff_k(const unsigned short* __restrict__ xr, int* flag) {
  __shared__ int cnt;
  if (threadIdx.x == 0) cnt = 0;
  __syncthreads();
  int local = 0;
  for (int i = threadIdx.x; i < 4096; i += 64) {
    const unsigned short u = xr[2 * i];
    const int e = (u >> 7) & 0xFF;
    if (e >= 0x70 && e <= 0x85) local++;
  }
  atomicAdd(&cnt, local);
  __syncthreads();
  if (threadIdx.x == 0) *flag = (cnt > 2048) ? 1 : 0;
}

// ---------- canonicalize x -> bf16 ----------
__global__ __launch_bounds__(256) void cvt_x_k(const void* __restrict__ src,
                                               bf16* __restrict__ dst,
                                               const int* __restrict__ flag, int n) {
  const bool isbf = (*flag != 0);
  const int stride = gridDim.x * blockDim.x * 8;
  for (int idx = (blockIdx.x * blockDim.x + threadIdx.x) * 8; idx < n; idx += stride) {
    bf16x8 o;
    if (isbf) {
      bf16x8 v = *(const bf16x8*)((const bf16*)src + idx);
      #pragma unroll
      for (int j = 0; j < 8; ++j) o[j] = (bf16)scrub((float)v[j]);
    } else {
      const float* s = (const float*)src + idx;
      #pragma unroll
      for (int j = 0; j < 8; ++j) o[j] = (bf16)scrub(s[j]);
    }
    *(bf16x8*)&dst[idx] = o;
  }
}

// ---------- 4-way transpose+canonicalize: dstz[n][k] = srcz[k][n] ----------
__global__ __launch_bounds__(256) void wtrans_cvt4_k(const void* __restrict__ W0,
                                                     const void* __restrict__ W1,
                                                     const void* __restrict__ W2,
                                                     const void* __restrict__ W3,
                                                     bf16* __restrict__ dstBase,
                                                     const int* __restrict__ flag) {
  __shared__ bf16 t[32][33];
  const bool isbf = (*flag != 0);
  const int z = blockIdx.z;
  const void* src = (z == 0) ? W0 : (z == 1) ? W1 : (z == 2) ? W2 : W3;
  bf16* dst = dstBase + (size_t)z * D * D;
  const int bx = blockIdx.x * 32, by = blockIdx.y * 32;
  const int tx = threadIdx.x & 31, ty = threadIdx.x >> 5;
  for (int i = ty; i < 32; i += 8) {
    const size_t off = (size_t)(by + i) * D + bx + tx;
    const float v = isbf ? (float)((const bf16*)src)[off] : ((const float*)src)[off];
    t[i][tx] = (bf16)scrub(v);
  }
  __syncthreads();
  for (int i = ty; i < 32; i += 8)
    dst[(size_t)(bx + i) * D + by + tx] = t[tx][i];
}

// ---------- per-head V transpose: VT[bh][d][l] = V[(b,l)][h*64+d] ----------
__global__ __launch_bounds__(256) void vtrans_k(const bf16* __restrict__ V,
                                                bf16* __restrict__ VT) {
  __shared__ __align__(16) bf16 t[64 * 72];
  const int l0 = blockIdx.x * 64, bh = blockIdx.y;
  const int b = bh >> 4, h = bh & 15;
  const int tid = threadIdx.x;
  #pragma unroll
  for (int i = 0; i < 2; ++i) {
    const int o = tid * 8 + i * 2048;
    const int lrow = o >> 6, dcol = o & 63;
    *(bf16x8*)&t[lrow * 72 + dcol] =
        *(const bf16x8*)&V[(size_t)(b * L + l0 + lrow) * D + h * 64 + dcol];
  }
  __syncthreads();
  const int d = tid >> 2, lg = (tid & 3) * 16;
  bf16x8 o0, o1;
  #pragma unroll
  for (int j = 0; j < 8; ++j) o0[j] = t[(lg + j) * 72 + d];
  #pragma unroll
  for (int j = 0; j < 8; ++j) o1[j] = t[(lg + 8 + j) * 72 + d];
  bf16* dst = VT + ((size_t)bh * DH + d) * L + l0 + lg;
  *(bf16x8*)dst = o0;
  *(bf16x8*)(dst + 8) = o1;
}

// ---------- fused QKV GEMM: [Q|K|V] = x @ [WqT|WkT|WvT]^T + b ----------
// Bt is the stacked [3072][1024] weight; buffer selected by n0>>10 (uniform).
// Q epilogue folds 1/sqrt(DH) * log2(e) = 0.125*1.4426950 (exp2-domain softmax).
__global__ __launch_bounds__(256) void qkv_gemm_k(const bf16* __restrict__ A,
                                                  const bf16* __restrict__ Bt,
                                                  const void* __restrict__ bq,
                                                  const void* __restrict__ bk,
                                                  const void* __restrict__ bv,
                                                  bf16* __restrict__ Q,
                                                  bf16* __restrict__ Kk,
                                                  bf16* __restrict__ V,
                                                  const int* __restrict__ flag) {
  __shared__ __align__(16) bf16 As[128 * BKg];
  __shared__ __align__(16) bf16 Bs[128 * BKg];
  const bool isbf = (*flag != 0);
  const int m0 = blockIdx.x * 128, n0 = blockIdx.y * 128;
  const int buf = n0 >> 10, nloc = n0 & 1023;
  bf16* Cb = (buf == 0) ? Q : (buf == 1) ? Kk : V;
  const void* bias = (buf == 0) ? bq : (buf == 1) ? bk : bv;
  const float scale = (buf == 0) ? 0.18033688011111f : 1.0f; // 0.125*log2(e)

  const int tid = threadIdx.x, wave = tid >> 6, lane = tid & 63;
  const int wr = wave >> 1, wc = wave & 1;
  const int quad = lane >> 4, l16 = lane & 15;
  const int srow = lane >> 3;
  const int scol = ((lane ^ srow) & 7) * 8;
  const int l7 = l16 & 7;
  const int s0 = ((quad ^ l7) * 8);
  const int s1 = s0 ^ 32;

  f32x4 acc[4][4] = {};

  for (int k0 = 0; k0 < GK; k0 += BKg) {
    for (int c = wave; c < 16; c += 4) {
      load_lds16(A  + (size_t)(m0 + c * 8 + srow) * GK + k0 + scol, &As[c * 512]);
      load_lds16(Bt + (size_t)(n0 + c * 8 + srow) * GK + k0 + scol, &Bs[c * 512]);
    }
    __syncthreads();
    #pragma unroll
    for (int kk = 0; kk < BKg; kk += 32) {
      const int sk = kk ? s1 : s0;
      bf16x8 af[4], bfr[4];
      #pragma unroll
      for (int i = 0; i < 4; ++i)
        af[i] = *(const bf16x8*)&As[(wr * 64 + i * 16 + l16) * BKg + sk];
      #pragma unroll
      for (int i = 0; i < 4; ++i)
        bfr[i] = *(const bf16x8*)&Bs[(wc * 64 + i * 16 + l16) * BKg + sk];
      #pragma unroll
      for (int mi = 0; mi < 4; ++mi)
        #pragma unroll
        for (int ni = 0; ni < 4; ++ni)
          acc[mi][ni] = mfma(af[mi], bfr[ni], acc[mi][ni]);
    }
    __syncthreads();
  }

  #pragma unroll
  for (int ni = 0; ni < 4; ++ni) {
    const int col = nloc + wc * 64 + ni * 16 + l16;
    const float bv2 = isbf ? (float)((const bf16*)bias)[col] : ((const float*)bias)[col];
    #pragma unroll
    for (int mi = 0; mi < 4; ++mi)
      #pragma unroll
      for (int r = 0; r < 4; ++r) {
        const int row = m0 + wr * 64 + mi * 16 + quad * 4 + r;
        Cb[(size_t)row * D + col] = (bf16)((acc[mi][ni][r] + bv2) * scale);
      }
  }
}

// ---------- final GEMM: out = attnO @ WoT^T + bo (dtype per flag) ----------
__global__ __launch_bounds__(256) void gemm_bt_k(const bf16* __restrict__ A,
                                                 const bf16* __restrict__ Bt,
                                                 const void* __restrict__ bias,
                                                 void* __restrict__ C,
                                                 const int* __restrict__ flag) {
  __shared__ __align__(16) bf16 As[128 * BKg];
  __shared__ __align__(16) bf16 Bs[128 * BKg];
  const bool isbf = (*flag != 0);
  const int m0 = blockIdx.x * 128, n0 = blockIdx.y * 128;
  const int tid = threadIdx.x, wave = tid >> 6, lane = tid & 63;
  const int wr = wave >> 1, wc = wave & 1;
  const int quad = lane >> 4, l16 = lane & 15;
  const int srow = lane >> 3;
  const int scol = ((lane ^ srow) & 7) * 8;
  const int l7 = l16 & 7;
  const int s0 = ((quad ^ l7) * 8);
  const int s1 = s0 ^ 32;

  f32x4 acc[4][4] = {};

  for (int k0 = 0; k0 < GK; k0 += BKg) {
    for (int c = wave; c < 16; c += 4) {
      load_lds16(A  + (size_t)(m0 + c * 8 + srow) * GK + k0 + scol, &As[c * 512]);
      load_lds16(Bt + (size_t)(n0 + c * 8 + srow) * GK + k0 + scol, &Bs[c * 512]);
    }
    __syncthreads();
    #pragma unroll
    for (int kk = 0; kk < BKg; kk += 32) {
      const int sk = kk ? s1 : s0;
      bf16x8 af[4], bfr[4];
      #pragma unroll
      for (int i = 0; i < 4; ++i)
        af[i] = *(const bf16x8*)&As[(wr * 64 + i * 16 + l16) * BKg + sk];
      #pragma unroll
      for (int i = 0; i < 4; ++i)
        bfr[i] = *(const bf16x8*)&Bs[(wc * 64 + i * 16 + l16) * BKg + sk];
      #pragma unroll
      for (int mi = 0; mi < 4; ++mi)
        #pragma unroll
        for (int ni = 0; ni < 4; ++ni)
          acc[mi][ni] = mfma(af[mi], bfr[ni], acc[mi][ni]);
    }
    __syncthreads();
  }

  bf16* Cb = (bf16*)C;
  float* Cf = (float*)C;
  #pragma unroll
  for (int ni = 0; ni < 4; ++ni) {
    const int col = n0 + wc * 64 + ni * 16 + l16;
    const float bv = isbf ? (float)((const bf16*)bias)[col] : ((const float*)bias)[col];
    #pragma unroll
    for (int mi = 0; mi < 4; ++mi)
      #pragma unroll
      for (int r = 0; r < 4; ++r) {
        const int row = m0 + wr * 64 + mi * 16 + quad * 4 + r;
        const float v = acc[mi][ni][r] + bv;
        if (isbf) Cb[(size_t)row * D + col] = (bf16)v;
        else      Cf[(size_t)row * D + col] = v;
      }
  }
}

// ---------- fused causal flash attention v6 ----------
// QBLK=128 (2 q-subtiles/wave), K/V double-buffered LDS, stage-ahead, one barrier
// per 64-key tile. S^T orientation; softmax in exp2 domain; MFMA ones row-sum;
// defer-max THR=8. K/V LDS frags shared by both q-subtiles.
__global__ __launch_bounds__(256) void attn_k(bf16* QO,
                                              const bf16* __restrict__ K,
                                              const bf16* __restrict__ VT) {
  __shared__ __align__(16) bf16 Ks[2][64 * DH];    // swizzled [key][d], dbuf
  __shared__ __align__(16) bf16 Vt[2][DH * 64];    // swizzled [d][key], dbuf
  __shared__ __align__(16) bf16 Ps[4][16 * PST];   // per-wave P [q][key], padded

  const int bx = blockIdx.x;
  const int qt = (L / 128 - 1) - (bx >> 6);        // longest blocks first
  const int bh = bx & 63;
  const int b = bh >> 4, h = bh & 15;
  const int tid = threadIdx.x, wave = tid >> 6, lane = tid & 63;
  const int quad = lane >> 4, l16 = lane & 15;
  const int srow = lane >> 3;
  const int scol = ((lane ^ srow) & 7) * 8;
  const int l7 = l16 & 7;
  const int s0 = ((quad ^ l7) * 8);
  const int s1 = s0 ^ 32;

  bf16* Qb = QO + (size_t)b * L * D + h * DH;
  const bf16* Kb = K + (size_t)b * L * D + h * DH;
  const bf16* VTg = VT + (size_t)bh * DH * L;

  // Q B-frags for both q-subtiles; 0.125*log2(e) scale folded in by QKV GEMM
  bf16x8 qf[2][2];
  #pragma unroll
  for (int sq = 0; sq < 2; ++sq) {
    const int qrow = qt * 128 + sq * 64 + wave * 16 + l16;
    qf[sq][0] = *(const bf16x8*)(Qb + (size_t)qrow * D + quad * 8);
    qf[sq][1] = *(const bf16x8*)(Qb + (size_t)qrow * D + 32 + quad * 8);
  }

  bf16x8 ones;
  #pragma unroll
  for (int j = 0; j < 8; ++j) ones[j] = (bf16)1.0f;

  float m_run[2] = {-INFINITY, -INFINITY};
  f32x4 o_acc[2][4] = {};
  f32x4 o_sum[2] = {};

  const int nkt = 2 * qt + 2;                      // 64-key tiles for this block

  // prologue: stage tile 0 into buf 0
  for (int c = wave; c < 8; c += 4) {
    load_lds16(Kb  + (size_t)(c * 8 + srow) * D + scol, &Ks[0][c * 512]);
    load_lds16(VTg + (size_t)(c * 8 + srow) * L + scol, &Vt[0][c * 512]);
  }
  __syncthreads();

  int cur = 0;
  for (int kt = 0; kt < nkt; ++kt) {
    // stage NEXT tile into the other buffer; latency hides under compute below,
    // drained by the single __syncthreads at the end of this iteration.
    if (kt + 1 < nkt) {
      const int kn = kt + 1;
      for (int c = wave; c < 8; c += 4) {
        load_lds16(Kb  + (size_t)(kn * 64 + c * 8 + srow) * D + scol,
                   &Ks[cur ^ 1][c * 512]);
        load_lds16(VTg + (size_t)(c * 8 + srow) * L + kn * 64 + scol,
                   &Vt[cur ^ 1][c * 512]);
      }
    }

    const bf16* Kc = &Ks[cur][0];
    const bf16* Vc = &Vt[cur][0];

    // K A-frags, shared by both q-subtiles
    bf16x8 kf0[4], kf1[4];
    #pragma unroll
    for (int nb = 0; nb < 4; ++nb) {
      kf0[nb] = *(const bf16x8*)&Kc[(nb * 16 + l16) * DH + s0];
      kf1[nb] = *(const bf16x8*)&Kc[(nb * 16 + l16) * DH + s1];
    }

    // V B-frags, shared by both q-subtiles
    bf16x8 vf0[4], vf1[4];
    #pragma unroll
    for (int db = 0; db < 4; ++db) {
      vf0[db] = *(const bf16x8*)&Vc[(db * 16 + l16) * 64 + s0];
      vf1[db] = *(const bf16x8*)&Vc[(db * 16 + l16) * 64 + s1];
    }

    bf16* Pw = &Ps[wave][0];

    #pragma unroll
    for (int sq = 0; sq < 2; ++sq) {
      if (sq == 0 && kt == 2 * qt + 1) continue;   // sub0 fully masked at last tile
      const bool diag = (kt == 2 * qt + sq);

      // S^T = K @ Q^T: s[nb][r] = S[key=nb*16+quad*4+r][q=l16]
      f32x4 s[4];
      #pragma unroll
      for (int nb = 0; nb < 4; ++nb) {
        f32x4 a = {};
        a = mfma(kf0[nb], qf[sq][0], a);
        a = mfma(kf1[nb], qf[sq][1], a);
        s[nb] = a;
      }

      if (diag) { // local causal mask within the diagonal 64x64 tile
        const int qloc = wave * 16 + l16;
        #pragma unroll
        for (int nb = 0; nb < 4; ++nb)
          #pragma unroll
          for (int r = 0; r < 4; ++r)
            if (nb * 16 + quad * 4 + r > qloc) s[nb][r] = -1e30f;
      }

      // tile max, then cross-quad reduce (q-row state lives in lane l16)
      float mx = -INFINITY;
      #pragma unroll
      for (int nb = 0; nb < 4; ++nb) {
        const float a = fmaxf(fmaxf(s[nb][0], s[nb][1]), fmaxf(s[nb][2], s[nb][3]));
        mx = fmaxf(mx, a);
      }
      mx = fmaxf(mx, __shfl_xor(mx, 16, 64));
      mx = fmaxf(mx, __shfl_xor(mx, 32, 64));

      // defer-max: rescale only when the max grows by more than THR=8 (log2)
      if (!__all(mx <= m_run[sq] + 8.f)) {
        const float mn = fmaxf(m_run[sq], mx);
        const float alpha = __builtin_amdgcn_exp2f(m_run[sq] - mn);
        m_run[sq] = mn;
        #pragma unroll
        for (int r = 0; r < 4; ++r) {
          const float ar = __shfl(alpha, quad * 4 + r, 64);
          o_sum[sq][r] *= ar;
          #pragma unroll
          for (int db = 0; db < 4; ++db) o_acc[sq][db][r] *= ar;
        }
      }

      // P = 2^(s - m), packed b64 writes in [q][key] layout
      #pragma unroll
      for (int nb = 0; nb < 4; ++nb) {
        bf16x4 pk;
        #pragma unroll
        for (int r = 0; r < 4; ++r)
          pk[r] = (bf16)__builtin_amdgcn_exp2f(s[nb][r] - m_run[sq]);
        *(bf16x4*)&Pw[l16 * PST + nb * 16 + quad * 4] = pk;
      }

      // O += P @ V ; row-sum += P @ 1 (MFMA pipe does the denominator)
      bf16x8 p0 = *(const bf16x8*)&Pw[l16 * PST + quad * 8];
      bf16x8 p1 = *(const bf16x8*)&Pw[l16 * PST + 32 + quad * 8];
      o_sum[sq] = mfma(p0, ones, o_sum[sq]);
      o_sum[sq] = mfma(p1, ones, o_sum[sq]);
      #pragma unroll
      for (int db = 0; db < 4; ++db) {
        o_acc[sq][db] = mfma(p0, vf0[db], o_acc[sq][db]);
        o_acc[sq][db] = mfma(p1, vf1[db], o_acc[sq][db]);
      }
    }

    // single barrier per tile: drains the stage-ahead loads (vmcnt 0) AND
    // ensures all waves are done reading buf[cur] before it is overwritten.
    __syncthreads();
    cur ^= 1;
  }

  #pragma unroll
  for (int sq = 0; sq < 2; ++sq)
    #pragma unroll
    for (int r = 0; r < 4; ++r) {
      const float inv = 1.f / o_sum[sq][r];  // shuffle-free: o_sum row == o_acc row
      const int row = qt * 128 + sq * 64 + wave * 16 + quad * 4 + r;
      #pragma unroll
      for (int db = 0; db < 4; ++db)
        Qb[(size_t)row * D + db * 16 + l16] = (bf16)(o_acc[sq][db][r] * inv);
    }
}

extern "C" void kernel_launch(void* const* d_in, const int* in_sizes, int n_in,
                              void* d_out, int out_size, void* d_ws, size_t ws_size,
                              hipStream_t stream) {
  const void* x  = d_in[0];
  const void* Wq = d_in[1];
  const void* bq = d_in[2];
  const void* Wk = d_in[3];
  const void* bk = d_in[4];
  const void* Wv = d_in[5];
  const void* bv = d_in[6];
  const void* Wo = d_in[7];
  const void* bo = d_in[8];
  // d_in[9] = causal mask, analytic

  int* flag = (int*)d_ws;
  char* p = (char*)d_ws + 4096;
  bf16* xc  = (bf16*)p;                 p += (size_t)BL * D * 2;
  bf16* WqT = (bf16*)p;                 p += (size_t)D * D * 2; // WqT/WkT/WvT/WoT
  bf16* WkT = (bf16*)p;                 p += (size_t)D * D * 2; // contiguous =
  bf16* WvT = (bf16*)p;                 p += (size_t)D * D * 2; // stacked [4096][1024]
  bf16* WoT = (bf16*)p;                 p += (size_t)D * D * 2;
  bf16* Qb  = (bf16*)p;                 p += (size_t)BL * D * 2; // O aliases Q
  bf16* Kb  = (bf16*)p;                 p += (size_t)BL * D * 2;
  bf16* Vb  = (bf16*)p;
  bf16* VTb = xc; // xc dead after QKV GEMM; reuse for V^T

  sniff_k<<<1, 64, 0, stream>>>((const unsigned short*)x, flag);

  cvt_x_k<<<1024, 256, 0, stream>>>(x, xc, flag, BL * D);
  wtrans_cvt4_k<<<dim3(32, 32, 4), 256, 0, stream>>>(Wq, Wk, Wv, Wo, WqT, flag);

  qkv_gemm_k<<<dim3(GM / 128, 3072 / 128), 256, 0, stream>>>(
      xc, WqT, bq, bk, bv, Qb, Kb, Vb, flag);

  vtrans_k<<<dim3(L / 64, B * H), 256, 0, stream>>>(Vb, VTb);

  attn_k<<<dim3((L / 128) * B * H), 256, 0, stream>>>(Qb, Kb, VTb);

  gemm_bt_k<<<dim3(GM / 128, D / 128), 256, 0, stream>>>(Qb, WoT, bo, d_out, flag);
}

// Round 5
// 300.030 us; speedup vs baseline: 1.0066x; 1.0066x over previous
//
#include <hip/hip_runtime.h>
#include <hip/hip_bf16.h>

// MHA: B=4 L=2048 D=1024 H=16 DH=64, causal. Inputs f32 (sniffed; dtype-proof).
// Round 12: in-register P on VERIFIED 16x16x32 intrinsics only.
// R11's 32x32 path failed with absmax 1.87e30 despite a boundedness proof that
// the math cannot exceed ~1e4 -> the unverified mfma32 register interface was
// the broken assumption. This round rebuilds the chain-kill (no P-LDS round
// trip) on the 16x16x32 layouts that R7/R8's passing kernels hardware-verified:
//  - QK^T (R8-exact): s[sub][r] = S[key=sub*16+quad*4+r][q=l16].
//  - P packed in-lane with plain (bf16) casts into PV A-frags fr0/fr1
//    (slot (quad,j) <- key (j<4 ? quad*4+j : 16+quad*4+j-4) + 32c).
//  - V^T stored POSITION-PERMUTED at vtrans (within each 32-key group, pos p
//    holds key ((p&4)>>2)*16 + (p>>3)*4 + (p&3)) so B slot keys match A slot
//    keys -- MFMA K-reduction is order-independent, A/B pair slot-to-slot.
//  - No P LDS (32KB total), R9-verified dbuf+prefetch+1-barrier staging,
//    exp2 domain, defer-max THR=8, MFMA-ones o_sum, shuffle-free epilogue.

typedef __bf16 bf16;
typedef __bf16 bf16x4 __attribute__((ext_vector_type(4)));
typedef __bf16 bf16x8 __attribute__((ext_vector_type(8)));
typedef float f32x4 __attribute__((ext_vector_type(4)));

#define DEV static __device__ __forceinline__

constexpr int B = 4, L = 2048, D = 1024, H = 16, DH = 64;
constexpr int BL = B * L;                      // 8192
constexpr int GM = 8192, GK = 1024;
constexpr int BKg = 64;                        // GEMM K-tile

typedef __attribute__((address_space(1))) const void* gptr1;
typedef __attribute__((address_space(3))) void* lptr3;

DEV void load_lds16(const bf16* g, bf16* l) {
  __builtin_amdgcn_global_load_lds((gptr1)g, (lptr3)l, 16, 0, 0);
}

DEV f32x4 mfma(bf16x8 a, bf16x8 b, f32x4 c) {
  return __builtin_amdgcn_mfma_f32_16x16x32_bf16(a, b, c, 0, 0, 0);
}

DEV float scrub(float v) { return (v == v) ? v : 0.f; }

// ---------- dtype sniff (flag=1: bf16 storage, 0: f32) ----------
__global__ void sniff_k(const unsigned short* __restrict__ xr, int* flag) {
  __shared__ int cnt;
  if (threadIdx.x == 0) cnt = 0;
  __syncthreads();
  int local = 0;
  for (int i = threadIdx.x; i < 4096; i += 64) {
    const unsigned short u = xr[2 * i];
    const int e = (u >> 7) & 0xFF;
    if (e >= 0x70 && e <= 0x85) local++;
  }
  atomicAdd(&cnt, local);
  __syncthreads();
  if (threadIdx.x == 0) *flag = (cnt > 2048) ? 1 : 0;
}

// ---------- canonicalize x -> bf16 ----------
__global__ __launch_bounds__(256) void cvt_x_k(const void* __restrict__ src,
                                               bf16* __restrict__ dst,
                                               const int* __restrict__ flag, int n) {
  const bool isbf = (*flag != 0);
  const int stride = gridDim.x * blockDim.x * 8;
  for (int idx = (blockIdx.x * blockDim.x + threadIdx.x) * 8; idx < n; idx += stride) {
    bf16x8 o;
    if (isbf) {
      bf16x8 v = *(const bf16x8*)((const bf16*)src + idx);
      #pragma unroll
      for (int j = 0; j < 8; ++j) o[j] = (bf16)scrub((float)v[j]);
    } else {
      const float* s = (const float*)src + idx;
      #pragma unroll
      for (int j = 0; j < 8; ++j) o[j] = (bf16)scrub(s[j]);
    }
    *(bf16x8*)&dst[idx] = o;
  }
}

// ---------- 4-way transpose+canonicalize: dstz[n][k] = srcz[k][n] ----------
__global__ __launch_bounds__(256) void wtrans_cvt4_k(const void* __restrict__ W0,
                                                     const void* __restrict__ W1,
                                                     const void* __restrict__ W2,
                                                     const void* __restrict__ W3,
                                                     bf16* __restrict__ dstBase,
                                                     const int* __restrict__ flag) {
  __shared__ bf16 t[32][33];
  const bool isbf = (*flag != 0);
  const int z = blockIdx.z;
  const void* src = (z == 0) ? W0 : (z == 1) ? W1 : (z == 2) ? W2 : W3;
  bf16* dst = dstBase + (size_t)z * D * D;
  const int bx = blockIdx.x * 32, by = blockIdx.y * 32;
  const int tx = threadIdx.x & 31, ty = threadIdx.x >> 5;
  for (int i = ty; i < 32; i += 8) {
    const size_t off = (size_t)(by + i) * D + bx + tx;
    const float v = isbf ? (float)((const bf16*)src)[off] : ((const float*)src)[off];
    t[i][tx] = (bf16)scrub(v);
  }
  __syncthreads();
  for (int i = ty; i < 32; i += 8)
    dst[(size_t)(bx + i) * D + by + tx] = t[tx][i];
}

// ---------- per-head V transpose, POSITION-PERMUTED ----------
// VT[bh][d][pos]: within each 32-key group, position p holds key
// key(p) = ((p&4)>>2)*16 + (p>>3)*4 + (p&3)   (bijection, self-derived twice).
// This makes the attention PV B-frag (contiguous 8 @ pos quad*8) hold exactly
// the keys the in-register A-frag (QK^T C-regs) holds at the same slots.
__global__ __launch_bounds__(256) void vtrans_k(const bf16* __restrict__ V,
                                                bf16* __restrict__ VT) {
  __shared__ __align__(16) bf16 t[64 * 72];
  const int l0 = blockIdx.x * 64, bh = blockIdx.y;
  const int b = bh >> 4, h = bh & 15;
  const int tid = threadIdx.x;
  #pragma unroll
  for (int i = 0; i < 2; ++i) {
    const int o = tid * 8 + i * 2048;
    const int lrow = o >> 6, dcol = o & 63;
    *(bf16x8*)&t[lrow * 72 + dcol] =
        *(const bf16x8*)&V[(size_t)(b * L + l0 + lrow) * D + h * 64 + dcol];
  }
  __syncthreads();
  const int d = tid >> 2, kc = tid & 3;      // kc: which 16-key slice
  const int G = kc >> 1, hh = kc & 1;        // 32-group, half within group
  bf16x8 o0, o1;                             // keys kc*16 + 0..7 / 8..15
  #pragma unroll
  for (int j = 0; j < 8; ++j) o0[j] = t[(kc * 16 + j) * 72 + d];
  #pragma unroll
  for (int j = 0; j < 8; ++j) o1[j] = t[(kc * 16 + 8 + j) * 72 + d];
  bf16* dst = VT + ((size_t)bh * DH + d) * L + l0 + G * 32;
  // key kc*16+i -> in-group pos (i>>2)*8 + hh*4 + (i&3)
  *(bf16x4*)(dst + hh * 4)      = __builtin_shufflevector(o0, o0, 0, 1, 2, 3);
  *(bf16x4*)(dst + 8 + hh * 4)  = __builtin_shufflevector(o0, o0, 4, 5, 6, 7);
  *(bf16x4*)(dst + 16 + hh * 4) = __builtin_shufflevector(o1, o1, 0, 1, 2, 3);
  *(bf16x4*)(dst + 24 + hh * 4) = __builtin_shufflevector(o1, o1, 4, 5, 6, 7);
}

// ---------- fused QKV GEMM: [Q|K|V] = x @ [WqT|WkT|WvT]^T + b ----------
__global__ __launch_bounds__(256) void qkv_gemm_k(const bf16* __restrict__ A,
                                                  const bf16* __restrict__ Bt,
                                                  const void* __restrict__ bq,
                                                  const void* __restrict__ bk,
                                                  const void* __restrict__ bv,
                                                  bf16* __restrict__ Q,
                                                  bf16* __restrict__ Kk,
                                                  bf16* __restrict__ V,
                                                  const int* __restrict__ flag) {
  __shared__ __align__(16) bf16 As[128 * BKg];
  __shared__ __align__(16) bf16 Bs[128 * BKg];
  const bool isbf = (*flag != 0);
  const int m0 = blockIdx.x * 128, n0 = blockIdx.y * 128;
  const int buf = n0 >> 10, nloc = n0 & 1023;
  bf16* Cb = (buf == 0) ? Q : (buf == 1) ? Kk : V;
  const void* bias = (buf == 0) ? bq : (buf == 1) ? bk : bv;
  const float scale = (buf == 0) ? 0.18033688011111f : 1.0f; // 0.125*log2(e)

  const int tid = threadIdx.x, wave = tid >> 6, lane = tid & 63;
  const int wr = wave >> 1, wc = wave & 1;
  const int quad = lane >> 4, l16 = lane & 15;
  const int srow = lane >> 3;
  const int scol = ((lane ^ srow) & 7) * 8;
  const int l7 = l16 & 7;
  const int s0 = ((quad ^ l7) * 8);
  const int s1 = s0 ^ 32;

  f32x4 acc[4][4] = {};

  for (int k0 = 0; k0 < GK; k0 += BKg) {
    for (int c = wave; c < 16; c += 4) {
      load_lds16(A  + (size_t)(m0 + c * 8 + srow) * GK + k0 + scol, &As[c * 512]);
      load_lds16(Bt + (size_t)(n0 + c * 8 + srow) * GK + k0 + scol, &Bs[c * 512]);
    }
    __syncthreads();
    #pragma unroll
    for (int kk = 0; kk < BKg; kk += 32) {
      const int sk = kk ? s1 : s0;
      bf16x8 af[4], bfr[4];
      #pragma unroll
      for (int i = 0; i < 4; ++i)
        af[i] = *(const bf16x8*)&As[(wr * 64 + i * 16 + l16) * BKg + sk];
      #pragma unroll
      for (int i = 0; i < 4; ++i)
        bfr[i] = *(const bf16x8*)&Bs[(wc * 64 + i * 16 + l16) * BKg + sk];
      #pragma unroll
      for (int mi = 0; mi < 4; ++mi)
        #pragma unroll
        for (int ni = 0; ni < 4; ++ni)
          acc[mi][ni] = mfma(af[mi], bfr[ni], acc[mi][ni]);
    }
    __syncthreads();
  }

  #pragma unroll
  for (int ni = 0; ni < 4; ++ni) {
    const int col = nloc + wc * 64 + ni * 16 + l16;
    const float bv2 = isbf ? (float)((const bf16*)bias)[col] : ((const float*)bias)[col];
    #pragma unroll
    for (int mi = 0; mi < 4; ++mi)
      #pragma unroll
      for (int r = 0; r < 4; ++r) {
        const int row = m0 + wr * 64 + mi * 16 + quad * 4 + r;
        Cb[(size_t)row * D + col] = (bf16)((acc[mi][ni][r] + bv2) * scale);
      }
  }
}

// ---------- final GEMM: out = attnO @ WoT^T + bo (dtype per flag) ----------
__global__ __launch_bounds__(256) void gemm_bt_k(const bf16* __restrict__ A,
                                                 const bf16* __restrict__ Bt,
                                                 const void* __restrict__ bias,
                                                 void* __restrict__ C,
                                                 const int* __restrict__ flag) {
  __shared__ __align__(16) bf16 As[128 * BKg];
  __shared__ __align__(16) bf16 Bs[128 * BKg];
  const bool isbf = (*flag != 0);
  const int m0 = blockIdx.x * 128, n0 = blockIdx.y * 128;
  const int tid = threadIdx.x, wave = tid >> 6, lane = tid & 63;
  const int wr = wave >> 1, wc = wave & 1;
  const int quad = lane >> 4, l16 = lane & 15;
  const int srow = lane >> 3;
  const int scol = ((lane ^ srow) & 7) * 8;
  const int l7 = l16 & 7;
  const int s0 = ((quad ^ l7) * 8);
  const int s1 = s0 ^ 32;

  f32x4 acc[4][4] = {};

  for (int k0 = 0; k0 < GK; k0 += BKg) {
    for (int c = wave; c < 16; c += 4) {
      load_lds16(A  + (size_t)(m0 + c * 8 + srow) * GK + k0 + scol, &As[c * 512]);
      load_lds16(Bt + (size_t)(n0 + c * 8 + srow) * GK + k0 + scol, &Bs[c * 512]);
    }
    __syncthreads();
    #pragma unroll
    for (int kk = 0; kk < BKg; kk += 32) {
      const int sk = kk ? s1 : s0;
      bf16x8 af[4], bfr[4];
      #pragma unroll
      for (int i = 0; i < 4; ++i)
        af[i] = *(const bf16x8*)&As[(wr * 64 + i * 16 + l16) * BKg + sk];
      #pragma unroll
      for (int i = 0; i < 4; ++i)
        bfr[i] = *(const bf16x8*)&Bs[(wc * 64 + i * 16 + l16) * BKg + sk];
      #pragma unroll
      for (int mi = 0; mi < 4; ++mi)
        #pragma unroll
        for (int ni = 0; ni < 4; ++ni)
          acc[mi][ni] = mfma(af[mi], bfr[ni], acc[mi][ni]);
    }
    __syncthreads();
  }

  bf16* Cb = (bf16*)C;
  float* Cf = (float*)C;
  #pragma unroll
  for (int ni = 0; ni < 4; ++ni) {
    const int col = n0 + wc * 64 + ni * 16 + l16;
    const float bv = isbf ? (float)((const bf16*)bias)[col] : ((const float*)bias)[col];
    #pragma unroll
    for (int mi = 0; mi < 4; ++mi)
      #pragma unroll
      for (int r = 0; r < 4; ++r) {
        const int row = m0 + wr * 64 + mi * 16 + quad * 4 + r;
        const float v = acc[mi][ni][r] + bv;
        if (isbf) Cb[(size_t)row * D + col] = (bf16)v;
        else      Cf[(size_t)row * D + col] = v;
      }
  }
}

// ---------- fused causal flash attention v8: 16x16, in-register P ----------
// R8 structure (64-q blocks, 4 waves x 16 q-rows, 64-key tiles, S^T per
// 16-key subtile) with the P LDS round-trip replaced by in-register packing:
// fr0/fr1 slots (quad,j) hold p for keys (j<4?quad*4+j:16+quad*4+j-4)+32c,
// matched by the position-permuted V^T. Dbuf + prefetch + 1 barrier/tile.
__global__ __launch_bounds__(256) void attn_k(bf16* QO,
                                              const bf16* __restrict__ K,
                                              const bf16* __restrict__ VT) {
  __shared__ __align__(16) bf16 Ks[2][64 * 64];    // swizzled [key][d], dbuf
  __shared__ __align__(16) bf16 Vt[2][64 * 64];    // swizzled [d][pos], dbuf

  const int bx = blockIdx.x;
  const int qt = (L / 64 - 1) - (bx >> 6);         // longest blocks first
  const int bh = bx & 63;
  const int b = bh >> 4, h = bh & 15;
  const int tid = threadIdx.x, wave = tid >> 6, lane = tid & 63;
  const int quad = lane >> 4, l16 = lane & 15;
  const int srow = lane >> 3;
  const int scol = ((lane ^ srow) & 7) * 8;
  const int l7 = l16 & 7;
  const int s0 = ((quad ^ l7) * 8);
  const int s1 = s0 ^ 32;

  bf16* Qb = QO + (size_t)b * L * D + h * DH;
  const bf16* Kb = K + (size_t)b * L * D + h * DH;
  const bf16* VTg = VT + (size_t)bh * DH * L;

  // Q B-frags (scale 0.125*log2e pre-folded by QKV GEMM)
  const int qrow = qt * 64 + wave * 16 + l16;
  const bf16x8 qf0 = *(const bf16x8*)(Qb + (size_t)qrow * D + quad * 8);
  const bf16x8 qf1 = *(const bf16x8*)(Qb + (size_t)qrow * D + 32 + quad * 8);

  bf16x8 ones;
  #pragma unroll
  for (int j = 0; j < 8; ++j) ones[j] = (bf16)1.0f;

  float m_run = -INFINITY;                // log2-domain max for q = l16
  f32x4 o_acc[4] = {};                    // C row=quad*4+r -> q, col=l16 -> d
  f32x4 o_sum = {};                       // MFMA row-sum, same layout

  const int nkt = qt + 1;

  // prologue: stage tile 0 into buf 0
  for (int c = wave; c < 8; c += 4) {
    load_lds16(Kb  + (size_t)(c * 8 + srow) * D + scol, &Ks[0][c * 512]);
    load_lds16(VTg + (size_t)(c * 8 + srow) * L + scol, &Vt[0][c * 512]);
  }
  __syncthreads();

  int cur = 0;
  for (int kt = 0; kt < nkt; ++kt) {
    if (kt + 1 < nkt) {                            // prefetch next tile
      for (int c = wave; c < 8; c += 4) {
        load_lds16(Kb  + (size_t)((kt + 1) * 64 + c * 8 + srow) * D + scol,
                   &Ks[cur ^ 1][c * 512]);
        load_lds16(VTg + (size_t)(c * 8 + srow) * L + (kt + 1) * 64 + scol,
                   &Vt[cur ^ 1][c * 512]);
      }
    }

    const bf16* Kc = &Ks[cur][0];
    const bf16* Vc = &Vt[cur][0];

    // S^T per 16-key subtile: s[sub][r] = S[key=sub*16+quad*4+r][q=l16]
    f32x4 s[4];
    #pragma unroll
    for (int sub = 0; sub < 4; ++sub) {
      bf16x8 k0 = *(const bf16x8*)&Kc[(sub * 16 + l16) * 64 + s0];
      bf16x8 k1 = *(const bf16x8*)&Kc[(sub * 16 + l16) * 64 + s1];
      f32x4 a = {};
      a = mfma(k0, qf0, a);
      a = mfma(k1, qf1, a);
      s[sub] = a;
    }

    if (kt == qt) { // diagonal causal mask (tile-local)
      const int qloc = wave * 16 + l16;
      #pragma unroll
      for (int sub = 0; sub < 4; ++sub)
        #pragma unroll
        for (int r = 0; r < 4; ++r)
          if (sub * 16 + quad * 4 + r > qloc) s[sub][r] = -1e30f;
    }

    // tile max, cross-quad reduce (state for q = l16)
    float mx = -INFINITY;
    #pragma unroll
    for (int sub = 0; sub < 4; ++sub) {
      const float a = fmaxf(fmaxf(s[sub][0], s[sub][1]), fmaxf(s[sub][2], s[sub][3]));
      mx = fmaxf(mx, a);
    }
    mx = fmaxf(mx, __shfl_xor(mx, 16, 64));
    mx = fmaxf(mx, __shfl_xor(mx, 32, 64));

    // defer-max: rescale only when max grows by more than 8 (log2 domain)
    if (!__all(mx <= m_run + 8.f)) {
      const float mn = fmaxf(m_run, mx);
      const float alpha = __builtin_amdgcn_exp2f(m_run - mn);
      m_run = mn;
      #pragma unroll
      for (int r = 0; r < 4; ++r) {
        const float ar = __shfl(alpha, quad * 4 + r, 64);
        o_sum[r] *= ar;
        #pragma unroll
        for (int db = 0; db < 4; ++db) o_acc[db][r] *= ar;
      }
    }

    // pack P in-register (A-frag slot (quad,j): key (j<4?quad*4+j:16+quad*4+j-4)+32c)
    bf16x8 fr0, fr1;
    #pragma unroll
    for (int r = 0; r < 4; ++r) {
      fr0[r]     = (bf16)__builtin_amdgcn_exp2f(s[0][r] - m_run);
      fr0[4 + r] = (bf16)__builtin_amdgcn_exp2f(s[1][r] - m_run);
      fr1[r]     = (bf16)__builtin_amdgcn_exp2f(s[2][r] - m_run);
      fr1[4 + r] = (bf16)__builtin_amdgcn_exp2f(s[3][r] - m_run);
    }

    // O += P @ V ; row-sum += P @ 1 (denominator on the MFMA pipe)
    o_sum = mfma(fr0, ones, o_sum);
    o_sum = mfma(fr1, ones, o_sum);
    #pragma unroll
    for (int db = 0; db < 4; ++db) {
      bf16x8 v0 = *(const bf16x8*)&Vc[(db * 16 + l16) * 64 + s0];
      bf16x8 v1 = *(const bf16x8*)&Vc[(db * 16 + l16) * 64 + s1];
      o_acc[db] = mfma(fr0, v0, o_acc[db]);
      o_acc[db] = mfma(fr1, v1, o_acc[db]);
    }

    // single barrier: drains prefetch AND protects buf reuse
    __syncthreads();
    cur ^= 1;
  }

  #pragma unroll
  for (int r = 0; r < 4; ++r) {
    const float inv = 1.f / o_sum[r];   // shuffle-free: o_sum row == o_acc row
    const int row = qt * 64 + wave * 16 + quad * 4 + r;
    #pragma unroll
    for (int db = 0; db < 4; ++db)
      Qb[(size_t)row * D + db * 16 + l16] = (bf16)(o_acc[db][r] * inv);
  }
}

extern "C" void kernel_launch(void* const* d_in, const int* in_sizes, int n_in,
                              void* d_out, int out_size, void* d_ws, size_t ws_size,
                              hipStream_t stream) {
  const void* x  = d_in[0];
  const void* Wq = d_in[1];
  const void* bq = d_in[2];
  const void* Wk = d_in[3];
  const void* bk = d_in[4];
  const void* Wv = d_in[5];
  const void* bv = d_in[6];
  const void* Wo = d_in[7];
  const void* bo = d_in[8];
  // d_in[9] = causal mask, analytic

  int* flag = (int*)d_ws;
  char* p = (char*)d_ws + 4096;
  bf16* xc  = (bf16*)p;                 p += (size_t)BL * D * 2;
  bf16* WqT = (bf16*)p;                 p += (size_t)D * D * 2; // WqT/WkT/WvT/WoT
  bf16* WkT = (bf16*)p;                 p += (size_t)D * D * 2; // contiguous =
  bf16* WvT = (bf16*)p;                 p += (size_t)D * D * 2; // stacked [4096][1024]
  bf16* WoT = (bf16*)p;                 p += (size_t)D * D * 2;
  bf16* Qb  = (bf16*)p;                 p += (size_t)BL * D * 2; // O aliases Q
  bf16* Kb  = (bf16*)p;                 p += (size_t)BL * D * 2;
  bf16* Vb  = (bf16*)p;
  bf16* VTb = xc; // xc dead after QKV GEMM; reuse for V^T

  sniff_k<<<1, 64, 0, stream>>>((const unsigned short*)x, flag);

  cvt_x_k<<<1024, 256, 0, stream>>>(x, xc, flag, BL * D);
  wtrans_cvt4_k<<<dim3(32, 32, 4), 256, 0, stream>>>(Wq, Wk, Wv, Wo, WqT, flag);

  qkv_gemm_k<<<dim3(GM / 128, 3072 / 128), 256, 0, stream>>>(
      xc, WqT, bq, bk, bv, Qb, Kb, Vb, flag);

  vtrans_k<<<dim3(L / 64, B * H), 256, 0, stream>>>(Vb, VTb);

  attn_k<<<dim3((L / 64) * B * H), 256, 0, stream>>>(Qb, Kb, VTb);

  gemm_bt_k<<<dim3(GM / 128, D / 128), 256, 0, stream>>>(Qb, WoT, bo, d_out, flag);
}

// Round 6
// 262.615 us; speedup vs baseline: 1.1500x; 1.1425x over previous
//
#include <hip/hip_runtime.h>
#include <hip/hip_bf16.h>

// MHA: B=4 L=2048 D=1024 H=16 DH=64, causal. Inputs f32 (sniffed; dtype-proof).
// Round 13: pipeline diet.
//  - vtrans_k ELIMINATED: qkv_gemm's V epilogue writes VT[bh][d][pos] directly
//    with the in-group key->position permutation (pos = 4*hi16 + 8*q4 + r,
//    contiguous bf16x4 per acc column). Saves ~64MB traffic + one launch.
//  - sniff_k widened to 4 waves (was 1 wave, 64 serial latency-bound loads).
//  - attn: max-reduce restructured into fmaxf triples (v_max3_f32 fusion).
// attn core unchanged from R12 (verified): in-register P on 16x16x32, no P-LDS,
// dbuf+prefetch+1 barrier/tile, exp2 domain, defer-max, MFMA-ones o_sum.

typedef __bf16 bf16;
typedef __bf16 bf16x4 __attribute__((ext_vector_type(4)));
typedef __bf16 bf16x8 __attribute__((ext_vector_type(8)));
typedef float f32x4 __attribute__((ext_vector_type(4)));

#define DEV static __device__ __forceinline__

constexpr int B = 4, L = 2048, D = 1024, H = 16, DH = 64;
constexpr int BL = B * L;                      // 8192
constexpr int GM = 8192, GK = 1024;
constexpr int BKg = 64;                        // GEMM K-tile

typedef __attribute__((address_space(1))) const void* gptr1;
typedef __attribute__((address_space(3))) void* lptr3;

DEV void load_lds16(const bf16* g, bf16* l) {
  __builtin_amdgcn_global_load_lds((gptr1)g, (lptr3)l, 16, 0, 0);
}

DEV f32x4 mfma(bf16x8 a, bf16x8 b, f32x4 c) {
  return __builtin_amdgcn_mfma_f32_16x16x32_bf16(a, b, c, 0, 0, 0);
}

DEV float scrub(float v) { return (v == v) ? v : 0.f; }
DEV float max3f(float a, float b, float c) { return fmaxf(fmaxf(a, b), c); }

// ---------- dtype sniff (flag=1: bf16 storage, 0: f32) ----------
__global__ void sniff_k(const unsigned short* __restrict__ xr, int* flag) {
  __shared__ int cnt;
  if (threadIdx.x == 0) cnt = 0;
  __syncthreads();
  int local = 0;
  for (int i = threadIdx.x; i < 4096; i += 256) {
    const unsigned short u = xr[2 * i];
    const int e = (u >> 7) & 0xFF;
    if (e >= 0x70 && e <= 0x85) local++;
  }
  atomicAdd(&cnt, local);
  __syncthreads();
  if (threadIdx.x == 0) *flag = (cnt > 2048) ? 1 : 0;
}

// ---------- canonicalize x -> bf16 ----------
__global__ __launch_bounds__(256) void cvt_x_k(const void* __restrict__ src,
                                               bf16* __restrict__ dst,
                                               const int* __restrict__ flag, int n) {
  const bool isbf = (*flag != 0);
  const int stride = gridDim.x * blockDim.x * 8;
  for (int idx = (blockIdx.x * blockDim.x + threadIdx.x) * 8; idx < n; idx += stride) {
    bf16x8 o;
    if (isbf) {
      bf16x8 v = *(const bf16x8*)((const bf16*)src + idx);
      #pragma unroll
      for (int j = 0; j < 8; ++j) o[j] = (bf16)scrub((float)v[j]);
    } else {
      const float* s = (const float*)src + idx;
      #pragma unroll
      for (int j = 0; j < 8; ++j) o[j] = (bf16)scrub(s[j]);
    }
    *(bf16x8*)&dst[idx] = o;
  }
}

// ---------- 4-way transpose+canonicalize: dstz[n][k] = srcz[k][n] ----------
__global__ __launch_bounds__(256) void wtrans_cvt4_k(const void* __restrict__ W0,
                                                     const void* __restrict__ W1,
                                                     const void* __restrict__ W2,
                                                     const void* __restrict__ W3,
                                                     bf16* __restrict__ dstBase,
                                                     const int* __restrict__ flag) {
  __shared__ bf16 t[32][33];
  const bool isbf = (*flag != 0);
  const int z = blockIdx.z;
  const void* src = (z == 0) ? W0 : (z == 1) ? W1 : (z == 2) ? W2 : W3;
  bf16* dst = dstBase + (size_t)z * D * D;
  const int bx = blockIdx.x * 32, by = blockIdx.y * 32;
  const int tx = threadIdx.x & 31, ty = threadIdx.x >> 5;
  for (int i = ty; i < 32; i += 8) {
    const size_t off = (size_t)(by + i) * D + bx + tx;
    const float v = isbf ? (float)((const bf16*)src)[off] : ((const float*)src)[off];
    t[i][tx] = (bf16)scrub(v);
  }
  __syncthreads();
  for (int i = ty; i < 32; i += 8)
    dst[(size_t)(bx + i) * D + by + tx] = t[tx][i];
}

// ---------- fused QKV GEMM: [Q|K|V] = x @ [WqT|WkT|WvT]^T + b ----------
// Q epilogue folds 0.125*log2(e); V epilogue writes VT[bh][d][pos] directly
// (per-32-key-group position permutation pos = 4*hi16 + 8*q4 + r, matching
// the attention PV A-frag slot order; bijection verified both directions).
__global__ __launch_bounds__(256) void qkv_gemm_k(const bf16* __restrict__ A,
                                                  const bf16* __restrict__ Bt,
                                                  const void* __restrict__ bq,
                                                  const void* __restrict__ bk,
                                                  const void* __restrict__ bv,
                                                  bf16* __restrict__ Q,
                                                  bf16* __restrict__ Kk,
                                                  bf16* __restrict__ VT,
                                                  const int* __restrict__ flag) {
  __shared__ __align__(16) bf16 As[128 * BKg];
  __shared__ __align__(16) bf16 Bs[128 * BKg];
  const bool isbf = (*flag != 0);
  const int m0 = blockIdx.x * 128, n0 = blockIdx.y * 128;
  const int buf = n0 >> 10, nloc = n0 & 1023;
  const void* bias = (buf == 0) ? bq : (buf == 1) ? bk : bv;
  const float scale = (buf == 0) ? 0.18033688011111f : 1.0f; // 0.125*log2(e)

  const int tid = threadIdx.x, wave = tid >> 6, lane = tid & 63;
  const int wr = wave >> 1, wc = wave & 1;
  const int quad = lane >> 4, l16 = lane & 15;
  const int srow = lane >> 3;
  const int scol = ((lane ^ srow) & 7) * 8;
  const int l7 = l16 & 7;
  const int s0 = ((quad ^ l7) * 8);
  const int s1 = s0 ^ 32;

  f32x4 acc[4][4] = {};

  for (int k0 = 0; k0 < GK; k0 += BKg) {
    for (int c = wave; c < 16; c += 4) {
      load_lds16(A  + (size_t)(m0 + c * 8 + srow) * GK + k0 + scol, &As[c * 512]);
      load_lds16(Bt + (size_t)(n0 + c * 8 + srow) * GK + k0 + scol, &Bs[c * 512]);
    }
    __syncthreads();
    #pragma unroll
    for (int kk = 0; kk < BKg; kk += 32) {
      const int sk = kk ? s1 : s0;
      bf16x8 af[4], bfr[4];
      #pragma unroll
      for (int i = 0; i < 4; ++i)
        af[i] = *(const bf16x8*)&As[(wr * 64 + i * 16 + l16) * BKg + sk];
      #pragma unroll
      for (int i = 0; i < 4; ++i)
        bfr[i] = *(const bf16x8*)&Bs[(wc * 64 + i * 16 + l16) * BKg + sk];
      #pragma unroll
      for (int mi = 0; mi < 4; ++mi)
        #pragma unroll
        for (int ni = 0; ni < 4; ++ni)
          acc[mi][ni] = mfma(af[mi], bfr[ni], acc[mi][ni]);
    }
    __syncthreads();
  }

  if (buf < 2) {
    bf16* Cb = (buf == 0) ? Q : Kk;
    #pragma unroll
    for (int ni = 0; ni < 4; ++ni) {
      const int col = nloc + wc * 64 + ni * 16 + l16;
      const float bv2 = isbf ? (float)((const bf16*)bias)[col] : ((const float*)bias)[col];
      #pragma unroll
      for (int mi = 0; mi < 4; ++mi)
        #pragma unroll
        for (int r = 0; r < 4; ++r) {
          const int row = m0 + wr * 64 + mi * 16 + quad * 4 + r;
          Cb[(size_t)row * D + col] = (bf16)((acc[mi][ni][r] + bv2) * scale);
        }
    }
  } else {
    // V -> VT[bh][d][pos], position-permuted, bf16x4 per acc column
    #pragma unroll
    for (int ni = 0; ni < 4; ++ni) {
      const int col = nloc + wc * 64 + ni * 16 + l16;   // feature c in [0,1024)
      const int h = col >> 6, d = col & 63;
      const float bv2 = isbf ? (float)((const bf16*)bias)[col] : ((const float*)bias)[col];
      #pragma unroll
      for (int mi = 0; mi < 4; ++mi) {
        const int row = m0 + wr * 64 + mi * 16 + quad * 4;  // token base, 4-aligned
        const int bb = row >> 11, l = row & 2047;
        const int pos = (l & ~31) + 4 * ((l >> 4) & 1) + 8 * ((l >> 2) & 3);
        bf16x4 pk;
        #pragma unroll
        for (int r = 0; r < 4; ++r) pk[r] = (bf16)(acc[mi][ni][r] + bv2);
        *(bf16x4*)&VT[((size_t)(bb * 16 + h) * 64 + d) * L + pos] = pk;
      }
    }
  }
}

// ---------- final GEMM: out = attnO @ WoT^T + bo (dtype per flag) ----------
__global__ __launch_bounds__(256) void gemm_bt_k(const bf16* __restrict__ A,
                                                 const bf16* __restrict__ Bt,
                                                 const void* __restrict__ bias,
                                                 void* __restrict__ C,
                                                 const int* __restrict__ flag) {
  __shared__ __align__(16) bf16 As[128 * BKg];
  __shared__ __align__(16) bf16 Bs[128 * BKg];
  const bool isbf = (*flag != 0);
  const int m0 = blockIdx.x * 128, n0 = blockIdx.y * 128;
  const int tid = threadIdx.x, wave = tid >> 6, lane = tid & 63;
  const int wr = wave >> 1, wc = wave & 1;
  const int quad = lane >> 4, l16 = lane & 15;
  const int srow = lane >> 3;
  const int scol = ((lane ^ srow) & 7) * 8;
  const int l7 = l16 & 7;
  const int s0 = ((quad ^ l7) * 8);
  const int s1 = s0 ^ 32;

  f32x4 acc[4][4] = {};

  for (int k0 = 0; k0 < GK; k0 += BKg) {
    for (int c = wave; c < 16; c += 4) {
      load_lds16(A  + (size_t)(m0 + c * 8 + srow) * GK + k0 + scol, &As[c * 512]);
      load_lds16(Bt + (size_t)(n0 + c * 8 + srow) * GK + k0 + scol, &Bs[c * 512]);
    }
    __syncthreads();
    #pragma unroll
    for (int kk = 0; kk < BKg; kk += 32) {
      const int sk = kk ? s1 : s0;
      bf16x8 af[4], bfr[4];
      #pragma unroll
      for (int i = 0; i < 4; ++i)
        af[i] = *(const bf16x8*)&As[(wr * 64 + i * 16 + l16) * BKg + sk];
      #pragma unroll
      for (int i = 0; i < 4; ++i)
        bfr[i] = *(const bf16x8*)&Bs[(wc * 64 + i * 16 + l16) * BKg + sk];
      #pragma unroll
      for (int mi = 0; mi < 4; ++mi)
        #pragma unroll
        for (int ni = 0; ni < 4; ++ni)
          acc[mi][ni] = mfma(af[mi], bfr[ni], acc[mi][ni]);
    }
    __syncthreads();
  }

  bf16* Cb = (bf16*)C;
  float* Cf = (float*)C;
  #pragma unroll
  for (int ni = 0; ni < 4; ++ni) {
    const int col = n0 + wc * 64 + ni * 16 + l16;
    const float bv = isbf ? (float)((const bf16*)bias)[col] : ((const float*)bias)[col];
    #pragma unroll
    for (int mi = 0; mi < 4; ++mi)
      #pragma unroll
      for (int r = 0; r < 4; ++r) {
        const int row = m0 + wr * 64 + mi * 16 + quad * 4 + r;
        const float v = acc[mi][ni][r] + bv;
        if (isbf) Cb[(size_t)row * D + col] = (bf16)v;
        else      Cf[(size_t)row * D + col] = v;
      }
  }
}

// ---------- fused causal flash attention v8.1: 16x16, in-register P ----------
// R12-verified core: S^T per 16-key subtile, in-register P pack into PV A-frags
// matched by position-permuted V^T; dbuf + prefetch + 1 barrier/tile; exp2
// domain; defer-max THR=8; MFMA-ones o_sum; shuffle-free epilogue.
// R13: max-reduce in fmaxf triples (v_max3 fusion).
__global__ __launch_bounds__(256) void attn_k(bf16* QO,
                                              const bf16* __restrict__ K,
                                              const bf16* __restrict__ VT) {
  __shared__ __align__(16) bf16 Ks[2][64 * 64];    // swizzled [key][d], dbuf
  __shared__ __align__(16) bf16 Vt[2][64 * 64];    // swizzled [d][pos], dbuf

  const int bx = blockIdx.x;
  const int qt = (L / 64 - 1) - (bx >> 6);         // longest blocks first
  const int bh = bx & 63;
  const int b = bh >> 4, h = bh & 15;
  const int tid = threadIdx.x, wave = tid >> 6, lane = tid & 63;
  const int quad = lane >> 4, l16 = lane & 15;
  const int srow = lane >> 3;
  const int scol = ((lane ^ srow) & 7) * 8;
  const int l7 = l16 & 7;
  const int s0 = ((quad ^ l7) * 8);
  const int s1 = s0 ^ 32;

  bf16* Qb = QO + (size_t)b * L * D + h * DH;
  const bf16* Kb = K + (size_t)b * L * D + h * DH;
  const bf16* VTg = VT + (size_t)bh * DH * L;

  // Q B-frags (scale 0.125*log2e pre-folded by QKV GEMM)
  const int qrow = qt * 64 + wave * 16 + l16;
  const bf16x8 qf0 = *(const bf16x8*)(Qb + (size_t)qrow * D + quad * 8);
  const bf16x8 qf1 = *(const bf16x8*)(Qb + (size_t)qrow * D + 32 + quad * 8);

  bf16x8 ones;
  #pragma unroll
  for (int j = 0; j < 8; ++j) ones[j] = (bf16)1.0f;

  float m_run = -INFINITY;                // log2-domain max for q = l16
  f32x4 o_acc[4] = {};                    // C row=quad*4+r -> q, col=l16 -> d
  f32x4 o_sum = {};                       // MFMA row-sum, same layout

  const int nkt = qt + 1;

  // prologue: stage tile 0 into buf 0
  for (int c = wave; c < 8; c += 4) {
    load_lds16(Kb  + (size_t)(c * 8 + srow) * D + scol, &Ks[0][c * 512]);
    load_lds16(VTg + (size_t)(c * 8 + srow) * L + scol, &Vt[0][c * 512]);
  }
  __syncthreads();

  int cur = 0;
  for (int kt = 0; kt < nkt; ++kt) {
    if (kt + 1 < nkt) {                            // prefetch next tile
      for (int c = wave; c < 8; c += 4) {
        load_lds16(Kb  + (size_t)((kt + 1) * 64 + c * 8 + srow) * D + scol,
                   &Ks[cur ^ 1][c * 512]);
        load_lds16(VTg + (size_t)(c * 8 + srow) * L + (kt + 1) * 64 + scol,
                   &Vt[cur ^ 1][c * 512]);
      }
    }

    const bf16* Kc = &Ks[cur][0];
    const bf16* Vc = &Vt[cur][0];

    // S^T per 16-key subtile: s[sub][r] = S[key=sub*16+quad*4+r][q=l16]
    f32x4 s[4];
    #pragma unroll
    for (int sub = 0; sub < 4; ++sub) {
      bf16x8 k0 = *(const bf16x8*)&Kc[(sub * 16 + l16) * 64 + s0];
      bf16x8 k1 = *(const bf16x8*)&Kc[(sub * 16 + l16) * 64 + s1];
      f32x4 a = {};
      a = mfma(k0, qf0, a);
      a = mfma(k1, qf1, a);
      s[sub] = a;
    }

    if (kt == qt) { // diagonal causal mask (tile-local)
      const int qloc = wave * 16 + l16;
      #pragma unroll
      for (int sub = 0; sub < 4; ++sub)
        #pragma unroll
        for (int r = 0; r < 4; ++r)
          if (sub * 16 + quad * 4 + r > qloc) s[sub][r] = -1e30f;
    }

    // tile max via max3 triples, then cross-quad reduce (state for q = l16)
    const float t0 = max3f(s[0][0], s[0][1], s[0][2]);
    const float t1 = max3f(s[0][3], s[1][0], s[1][1]);
    const float t2 = max3f(s[1][2], s[1][3], s[2][0]);
    const float t3 = max3f(s[2][1], s[2][2], s[2][3]);
    const float t4 = max3f(s[3][0], s[3][1], s[3][2]);
    float mx = fmaxf(max3f(t0, t1, t2), max3f(t3, t4, s[3][3]));
    mx = fmaxf(mx, __shfl_xor(mx, 16, 64));
    mx = fmaxf(mx, __shfl_xor(mx, 32, 64));

    // defer-max: rescale only when max grows by more than 8 (log2 domain)
    if (!__all(mx <= m_run + 8.f)) {
      const float mn = fmaxf(m_run, mx);
      const float alpha = __builtin_amdgcn_exp2f(m_run - mn);
      m_run = mn;
      #pragma unroll
      for (int r = 0; r < 4; ++r) {
        const float ar = __shfl(alpha, quad * 4 + r, 64);
        o_sum[r] *= ar;
        #pragma unroll
        for (int db = 0; db < 4; ++db) o_acc[db][r] *= ar;
      }
    }

    // pack P in-register (A-frag slot (quad,j): key (j<4?quad*4+j:16+quad*4+j-4)+32c)
    bf16x8 fr0, fr1;
    #pragma unroll
    for (int r = 0; r < 4; ++r) {
      fr0[r]     = (bf16)__builtin_amdgcn_exp2f(s[0][r] - m_run);
      fr0[4 + r] = (bf16)__builtin_amdgcn_exp2f(s[1][r] - m_run);
      fr1[r]     = (bf16)__builtin_amdgcn_exp2f(s[2][r] - m_run);
      fr1[4 + r] = (bf16)__builtin_amdgcn_exp2f(s[3][r] - m_run);
    }

    // O += P @ V ; row-sum += P @ 1 (denominator on the MFMA pipe)
    o_sum = mfma(fr0, ones, o_sum);
    o_sum = mfma(fr1, ones, o_sum);
    #pragma unroll
    for (int db = 0; db < 4; ++db) {
      bf16x8 v0 = *(const bf16x8*)&Vc[(db * 16 + l16) * 64 + s0];
      bf16x8 v1 = *(const bf16x8*)&Vc[(db * 16 + l16) * 64 + s1];
      o_acc[db] = mfma(fr0, v0, o_acc[db]);
      o_acc[db] = mfma(fr1, v1, o_acc[db]);
    }

    // single barrier: drains prefetch AND protects buf reuse
    __syncthreads();
    cur ^= 1;
  }

  #pragma unroll
  for (int r = 0; r < 4; ++r) {
    const float inv = 1.f / o_sum[r];   // shuffle-free: o_sum row == o_acc row
    const int row = qt * 64 + wave * 16 + quad * 4 + r;
    #pragma unroll
    for (int db = 0; db < 4; ++db)
      Qb[(size_t)row * D + db * 16 + l16] = (bf16)(o_acc[db][r] * inv);
  }
}

extern "C" void kernel_launch(void* const* d_in, const int* in_sizes, int n_in,
                              void* d_out, int out_size, void* d_ws, size_t ws_size,
                              hipStream_t stream) {
  const void* x  = d_in[0];
  const void* Wq = d_in[1];
  const void* bq = d_in[2];
  const void* Wk = d_in[3];
  const void* bk = d_in[4];
  const void* Wv = d_in[5];
  const void* bv = d_in[6];
  const void* Wo = d_in[7];
  const void* bo = d_in[8];
  // d_in[9] = causal mask, analytic

  int* flag = (int*)d_ws;
  char* p = (char*)d_ws + 4096;
  bf16* xc  = (bf16*)p;                 p += (size_t)BL * D * 2;
  bf16* WqT = (bf16*)p;                 p += (size_t)D * D * 2; // WqT/WkT/WvT/WoT
  bf16* WkT = (bf16*)p;                 p += (size_t)D * D * 2; // contiguous =
  bf16* WvT = (bf16*)p;                 p += (size_t)D * D * 2; // stacked [4096][1024]
  bf16* WoT = (bf16*)p;                 p += (size_t)D * D * 2;
  bf16* Qb  = (bf16*)p;                 p += (size_t)BL * D * 2; // O aliases Q
  bf16* Kb  = (bf16*)p;                 p += (size_t)BL * D * 2;
  bf16* VTb = (bf16*)p;                 // V^T written directly by qkv_gemm

  sniff_k<<<1, 256, 0, stream>>>((const unsigned short*)x, flag);

  cvt_x_k<<<1024, 256, 0, stream>>>(x, xc, flag, BL * D);
  wtrans_cvt4_k<<<dim3(32, 32, 4), 256, 0, stream>>>(Wq, Wk, Wv, Wo, WqT, flag);

  qkv_gemm_k<<<dim3(GM / 128, 3072 / 128), 256, 0, stream>>>(
      xc, WqT, bq, bk, bv, Qb, Kb, VTb, flag);

  attn_k<<<dim3((L / 64) * B * H), 256, 0, stream>>>(Qb, Kb, VTb);

  gemm_bt_k<<<dim3(GM / 128, D / 128), 256, 0, stream>>>(Qb, WoT, bo, d_out, flag);
}